// Round 2
// baseline (83.413 us; speedup 1.0000x reference)
//
#include <hip/hip_runtime.h>
#include <stdint.h>

#define N_   64
#define C_   64
#define W_   4096
#define F_   64
#define WW_  9
#define OW_  4088        // W_ - WW_ + 1
#define WBLK 128
#define WROWS 136        // WBLK + 8 halo
#define NWB  32          // OW_/WBLK rounded up

typedef __bf16 bf16x8 __attribute__((ext_vector_type(8)));
typedef float  f32x4  __attribute__((ext_vector_type(4)));

__device__ __forceinline__ unsigned short f2bf(float f) {
    union { float f; uint32_t u; } v; v.f = f;
    uint32_t u = v.u;
    return (unsigned short)((u + 0x7FFFu + ((u >> 16) & 1u)) >> 16);  // RNE
}

// filt fp32 [F][C][WW] -> filtT bf16 [t][f][c]  (B-fragments 16B-contiguous in c)
__global__ __launch_bounds__(256) void prep_filt_k(const float* __restrict__ filt,
                                                   unsigned short* __restrict__ filtT) {
    int id = blockIdx.x * 256 + threadIdx.x;
    if (id < WW_ * F_ * C_) {
        int t   = id >> 12;
        int rem = id & 4095;
        int f   = rem >> 6;
        int c   = rem & 63;
        filtT[id] = f2bf(filt[(f * C_ + c) * WW_ + t]);
    }
}

// x fp32 [N][C][W] -> xT bf16 [N][W][64c], chunk-XOR pre-swizzled:
//   element (n,w,c) stored at n*W*64 + w*64 + (((c>>3)^(w&7))<<3 | (c&7))
// Thread: 4c x 4w micro-tile, register transpose. No LDS.
__global__ __launch_bounds__(256) void xpose_k(const float* __restrict__ x,
                                               unsigned short* __restrict__ xT) {
    const int t  = threadIdx.x;
    const int n  = blockIdx.y;
    const int w0 = blockIdx.x * 64;
    const int c4 = (t & 15) * 4;          // this thread's 4 c-rows
    const int w  = w0 + (t >> 4) * 4;     // this thread's 4 w-cols

    const float* bp = x + ((size_t)n * C_ + c4) * W_ + w;
    float4 r0 = *reinterpret_cast<const float4*>(bp);
    float4 r1 = *reinterpret_cast<const float4*>(bp + W_);
    float4 r2 = *reinterpret_cast<const float4*>(bp + 2 * W_);
    float4 r3 = *reinterpret_cast<const float4*>(bp + 3 * W_);

    unsigned short* ob = xT + (size_t)n * W_ * 64;
    const int cg = c4 >> 3;               // chunk base (c>>3)
    const int cs = c4 & 7;                // 0 or 4

#define STORE_J(j, e0, e1, e2, e3) {                                      \
        int wj = w + (j);                                                 \
        int chunk = cg ^ (wj & 7);                                        \
        ushort4 u;                                                        \
        u.x = f2bf(e0); u.y = f2bf(e1); u.z = f2bf(e2); u.w = f2bf(e3);   \
        *reinterpret_cast<ushort4*>(ob + (size_t)wj * 64 + chunk * 8 + cs) = u; }

    STORE_J(0, r0.x, r1.x, r2.x, r3.x)
    STORE_J(1, r0.y, r1.y, r2.y, r3.y)
    STORE_J(2, r0.z, r1.z, r2.z, r3.z)
    STORE_J(3, r0.w, r1.w, r2.w, r3.w)
#undef STORE_J
}

// Main: one block = one n, 128 outputs-wide, all 64 filters. Staging = linear 17KB copy.
__global__ __launch_bounds__(256) void conv_fast_k(const unsigned short* __restrict__ xT,
                                                   const unsigned short* __restrict__ filtT,
                                                   const float* __restrict__ bias,
                                                   float* __restrict__ out) {
    __shared__ unsigned short xs[WROWS * 64];   // 17408 B, pre-swizzled rows of 128B

    const int tid  = threadIdx.x;
    const int n    = blockIdx.y;
    const int w0   = blockIdx.x * WBLK;
    const int lane = tid & 63;
    const int wv   = tid >> 6;

    // ---- stage: 17 x 1KB linear segments, round-robin over 4 waves ----
    const char* gsrc = (const char*)(xT + ((size_t)n * W_ + w0) * 64);
    char* lbase = (char*)xs;
    int4 stg[5];
    #pragma unroll
    for (int k = 0; k < 5; ++k) {
        int it = wv + k * 4;
        if (it < 17) stg[k] = *reinterpret_cast<const int4*>(gsrc + it * 1024 + lane * 16);
    }
    #pragma unroll
    for (int k = 0; k < 5; ++k) {
        int it = wv + k * 4;
        if (it < 17) *reinterpret_cast<int4*>(lbase + it * 1024 + lane * 16) = stg[k];
    }
    __syncthreads();

    const int f0  = (wv & 1) * 32;
    const int whb = (wv >> 1) * 64;
    const int l15 = lane & 15;
    const int lg  = lane >> 4;

    f32x4 acc[4][2];
    #pragma unroll
    for (int s = 0; s < 4; ++s)
        #pragma unroll
        for (int u = 0; u < 2; ++u)
            acc[s][u] = (f32x4){0.f, 0.f, 0.f, 0.f};

    #pragma unroll
    for (int t = 0; t < WW_; ++t) {
        #pragma unroll
        for (int m = 0; m < 2; ++m) {
            const unsigned short* bp = filtT + t * (F_ * C_) + (f0 + l15) * C_ + m * 32 + lg * 8;
            bf16x8 b0 = *reinterpret_cast<const bf16x8*>(bp);
            bf16x8 b1 = *reinterpret_cast<const bf16x8*>(bp + 16 * C_);
            #pragma unroll
            for (int s = 0; s < 4; ++s) {
                int row   = whb + s * 16 + l15 + t;               // <= 135
                int chunk = ((m << 2) + lg) ^ (row & 7);
                bf16x8 a  = *reinterpret_cast<const bf16x8*>(&xs[row * 64 + chunk * 8]);
                acc[s][0] = __builtin_amdgcn_mfma_f32_16x16x32_bf16(a, b0, acc[s][0], 0, 0, 0);
                acc[s][1] = __builtin_amdgcn_mfma_f32_16x16x32_bf16(a, b1, acc[s][1], 0, 0, 0);
            }
        }
    }

    #pragma unroll
    for (int u = 0; u < 2; ++u) {
        int f = f0 + u * 16 + l15;
        float bv = 64.0f * bias[f];
        #pragma unroll
        for (int s = 0; s < 4; ++s) {
            int wg = w0 + whb + s * 16 + lg * 4;
            if (wg < OW_) {
                float4 o;
                o.x = acc[s][u][0] + bv;
                o.y = acc[s][u][1] + bv;
                o.z = acc[s][u][2] + bv;
                o.w = acc[s][u][3] + bv;
                *reinterpret_cast<float4*>(out + ((n * F_ + f) * OW_ + wg)) = o;
            }
        }
    }
}

// ---------------- fallback (round-1 kernel, in-block transpose) ----------------
__global__ __launch_bounds__(256) void conv_fb_k(const float* __restrict__ x,
                                                 const unsigned short* __restrict__ filtT,
                                                 const float* __restrict__ bias,
                                                 float* __restrict__ out) {
    __shared__ unsigned short xs[WROWS * 64];
    const int tid = threadIdx.x;
    const int n   = blockIdx.y;
    const int w0  = blockIdx.x * WBLK;

    #pragma unroll
    for (int i = 0; i < 9; ++i) {
        int e4 = i * 256 + tid;
        if (e4 < 34 * 64) {
            int c  = e4 / 34;
            int w4 = e4 - c * 34;
            int wl = w4 * 4;
            int gw = w0 + wl;
            const float* xp = x + ((n * C_ + c) * W_ + gw);
            float4 v;
            if (gw + 3 < W_) {
                v = *reinterpret_cast<const float4*>(xp);
            } else {
                v.x = (gw + 0 < W_) ? xp[0] : 0.0f;
                v.y = (gw + 1 < W_) ? xp[1] : 0.0f;
                v.z = (gw + 2 < W_) ? xp[2] : 0.0f;
                v.w = (gw + 3 < W_) ? xp[3] : 0.0f;
            }
            unsigned short h[4] = { f2bf(v.x), f2bf(v.y), f2bf(v.z), f2bf(v.w) };
            #pragma unroll
            for (int j = 0; j < 4; ++j) {
                int w = wl + j;
                xs[w * 64 + ((((c >> 3) ^ (w & 7)) << 3) | (c & 7))] = h[j];
            }
        }
    }
    __syncthreads();

    const int lane = tid & 63;
    const int wv   = tid >> 6;
    const int f0   = (wv & 1) * 32;
    const int whb  = (wv >> 1) * 64;
    const int l15  = lane & 15;
    const int lg   = lane >> 4;

    f32x4 acc[4][2];
    #pragma unroll
    for (int s = 0; s < 4; ++s)
        #pragma unroll
        for (int u = 0; u < 2; ++u)
            acc[s][u] = (f32x4){0.f, 0.f, 0.f, 0.f};

    #pragma unroll
    for (int t = 0; t < WW_; ++t) {
        #pragma unroll
        for (int m = 0; m < 2; ++m) {
            const unsigned short* bp = filtT + t * (F_ * C_) + (f0 + l15) * C_ + m * 32 + lg * 8;
            bf16x8 b0 = *reinterpret_cast<const bf16x8*>(bp);
            bf16x8 b1 = *reinterpret_cast<const bf16x8*>(bp + 16 * C_);
            #pragma unroll
            for (int s = 0; s < 4; ++s) {
                int row   = whb + s * 16 + l15 + t;
                int chunk = ((m << 2) + lg) ^ (row & 7);
                bf16x8 a  = *reinterpret_cast<const bf16x8*>(&xs[row * 64 + chunk * 8]);
                acc[s][0] = __builtin_amdgcn_mfma_f32_16x16x32_bf16(a, b0, acc[s][0], 0, 0, 0);
                acc[s][1] = __builtin_amdgcn_mfma_f32_16x16x32_bf16(a, b1, acc[s][1], 0, 0, 0);
            }
        }
    }

    #pragma unroll
    for (int u = 0; u < 2; ++u) {
        int f = f0 + u * 16 + l15;
        float bv = 64.0f * bias[f];
        #pragma unroll
        for (int s = 0; s < 4; ++s) {
            int wg = w0 + whb + s * 16 + lg * 4;
            if (wg < OW_) {
                float4 o;
                o.x = acc[s][u][0] + bv;
                o.y = acc[s][u][1] + bv;
                o.z = acc[s][u][2] + bv;
                o.w = acc[s][u][3] + bv;
                *reinterpret_cast<float4*>(out + ((n * F_ + f) * OW_ + wg)) = o;
            }
        }
    }
}

extern "C" void kernel_launch(void* const* d_in, const int* in_sizes, int n_in,
                              void* d_out, int out_size, void* d_ws, size_t ws_size,
                              hipStream_t stream) {
    const float* x    = (const float*)d_in[0];
    const float* filt = (const float*)d_in[1];
    const float* bias = (const float*)d_in[2];
    float* out        = (float*)d_out;

    unsigned short* filtT = (unsigned short*)d_ws;            // 73728 B at offset 0
    const size_t XT_OFF = 73728;                              // 256B-aligned
    const size_t XT_B   = (size_t)N_ * W_ * 64 * 2;           // 33554432 B
    const size_t NEED   = XT_OFF + XT_B + 2048;               // pad for halo overrun

    prep_filt_k<<<(WW_ * F_ * C_ + 255) / 256, 256, 0, stream>>>(filt, filtT);

    if (ws_size >= NEED) {
        unsigned short* xT = (unsigned short*)((char*)d_ws + XT_OFF);
        dim3 gx(W_ / 64, N_);
        xpose_k<<<gx, 256, 0, stream>>>(x, xT);
        dim3 grid(NWB, N_);
        conv_fast_k<<<grid, 256, 0, stream>>>(xT, filtT, bias, out);
    } else {
        dim3 grid(NWB, N_);
        conv_fb_k<<<grid, 256, 0, stream>>>(x, filtT, bias, out);
    }
}

// Round 3
// 55.002 us; speedup vs baseline: 1.5165x; 1.5165x over previous
//
#include <hip/hip_runtime.h>
#include <stdint.h>

#define N_   64
#define C_   64
#define W_   4096
#define F_   64
#define WW_  9
#define OW_  4088        // W_ - WW_ + 1
#define WBLK 128
#define WROWS 136        // WBLK + 8 halo
#define TILES 2
#define STRIPES 16       // 32 w-tiles / TILES

typedef __bf16 bf16x8 __attribute__((ext_vector_type(8)));
typedef float  f32x4  __attribute__((ext_vector_type(4)));

__device__ __forceinline__ unsigned short f2bf(float f) {
    union { float f; uint32_t u; } v; v.f = f;
    uint32_t u = v.u;
    return (unsigned short)((u + 0x7FFFu + ((u >> 16) & 1u)) >> 16);  // RNE
}

// filt fp32 [F][C][WW] -> filtB bf16, fragment-major [t][f0h][m][u][lane][8j]
//   f = f0h*32 + u*16 + (lane&15),  c = m*32 + (lane>>4)*8 + j
// so each B-fragment load in the main kernel is ONE contiguous 1KB wave load.
__global__ __launch_bounds__(256) void prep_filt_k(const float* __restrict__ filt,
                                                   unsigned short* __restrict__ filtB) {
    int id = blockIdx.x * 256 + threadIdx.x;
    if (id < WW_ * F_ * C_) {
        int j    = id & 7;
        int lane = (id >> 3) & 63;
        int u    = (id >> 9) & 1;
        int m    = (id >> 10) & 1;
        int f0h  = (id >> 11) & 1;
        int t    = id >> 12;
        int l15  = lane & 15, lg = lane >> 4;
        int f = f0h * 32 + u * 16 + l15;
        int c = m * 32 + lg * 8 + j;
        filtB[id] = f2bf(filt[(f * C_ + c) * WW_ + t]);
    }
}

// One block: n = blockIdx.y, 2 w-tiles of 128 outputs, all 64 filters.
// Double-buffered LDS; async-stage split (issue loads early, write late);
// B-fragments double-buffered over t (prefetch t+1 during t's MFMAs).
__global__ __launch_bounds__(256, 3) void conv_k(const float* __restrict__ x,
                                                 const unsigned short* __restrict__ filtB,
                                                 const float* __restrict__ bias,
                                                 float* __restrict__ out) {
    __shared__ unsigned short xs[2][WROWS * 64];   // 2 x 17408 B, swizzled rows of 128B

    const int tid   = threadIdx.x;
    const int lane  = tid & 63;
    const int wv    = tid >> 6;
    const int n     = blockIdx.y;
    const int wbase = blockIdx.x * (TILES * WBLK);
    const int f0h   = wv & 1;              // wave's 32-filter half
    const int whb   = (wv >> 1) * 64;      // wave's 64-w half (local)
    const int l15   = lane & 15;
    const int lg    = lane >> 4;

    // staging map: iter i covers c = i*8 + (tid>>5), w = (tid&31)*4 .. +3
    const int sc0 = tid >> 5;              // 0..7  (= c & 7 for every iter)
    const int sw  = (tid & 31) << 2;       // 0..124
    const int hc  = tid >> 1;              // halo c (tid<128)
    const int hwo = 128 + (tid & 1) * 4;   // halo w offset

    const float* xrow = x + ((size_t)(n * C_ + sc0)) * W_;
    const unsigned short* Bb = filtB + f0h * 2048 + lane * 8;

    const float bv0 = 64.0f * bias[f0h * 32 + l15];        // C * bias (ref adds per channel)
    const float bv1 = 64.0f * bias[f0h * 32 + 16 + l15];

    float4 r[8];
    float4 rh;

    auto LOADS = [&](int w0) {
        #pragma unroll
        for (int i = 0; i < 8; ++i)
            r[i] = *reinterpret_cast<const float4*>(xrow + (size_t)i * 8 * W_ + w0 + sw);
        if (tid < 128) {
            int hw = w0 + hwo;
            if (hw < W_) rh = *reinterpret_cast<const float4*>(x + ((size_t)(n * C_ + hc)) * W_ + hw);
            else         rh = (float4){0.f, 0.f, 0.f, 0.f};
        }
    };

    auto WRITE = [&](int b) {
        unsigned short* dst = xs[b];
        #pragma unroll
        for (int i = 0; i < 8; ++i) {      // c = i*8 + sc0 -> chunk=i, sub=sc0
            const float* rp = &r[i].x;
            #pragma unroll
            for (int j = 0; j < 4; ++j) {
                int w = sw + j;
                dst[w * 64 + (((i ^ (w & 7)) << 3) | sc0)] = f2bf(rp[j]);
            }
        }
        if (tid < 128) {
            int cg = hc >> 3, cs = hc & 7;
            const float* rp = &rh.x;
            #pragma unroll
            for (int j = 0; j < 4; ++j) {
                int w = hwo + j;
                dst[w * 64 + (((cg ^ (w & 7)) << 3) | cs)] = f2bf(rp[j]);
            }
        }
    };

    auto COMPUTE = [&](int b, int w0) {
        const unsigned short* src = xs[b];
        f32x4 acc[4][2];
        #pragma unroll
        for (int s = 0; s < 4; ++s) {
            acc[s][0] = (f32x4){0.f, 0.f, 0.f, 0.f};
            acc[s][1] = (f32x4){0.f, 0.f, 0.f, 0.f};
        }
        bf16x8 Bc[4], Bn[4];
        #pragma unroll
        for (int q = 0; q < 4; ++q)        // frag (m=q>>1, u=q&1) for t=0
            Bc[q] = *reinterpret_cast<const bf16x8*>(Bb + (q >> 1) * 1024 + (q & 1) * 512);
        #pragma unroll
        for (int t = 0; t < WW_; ++t) {
            if (t < WW_ - 1) {
                #pragma unroll
                for (int q = 0; q < 4; ++q)
                    Bn[q] = *reinterpret_cast<const bf16x8*>(Bb + (t + 1) * 4096 + (q >> 1) * 1024 + (q & 1) * 512);
            }
            #pragma unroll
            for (int m = 0; m < 2; ++m) {
                #pragma unroll
                for (int s = 0; s < 4; ++s) {
                    int row   = whb + s * 16 + l15 + t;              // <= 135
                    int chunk = ((m << 2) | lg) ^ (row & 7);
                    bf16x8 a  = *reinterpret_cast<const bf16x8*>(&src[row * 64 + chunk * 8]);
                    acc[s][0] = __builtin_amdgcn_mfma_f32_16x16x32_bf16(a, Bc[m * 2 + 0], acc[s][0], 0, 0, 0);
                    acc[s][1] = __builtin_amdgcn_mfma_f32_16x16x32_bf16(a, Bc[m * 2 + 1], acc[s][1], 0, 0, 0);
                }
            }
            if (t < WW_ - 1) {
                #pragma unroll
                for (int q = 0; q < 4; ++q) Bc[q] = Bn[q];
            }
        }
        // epilogue: D col=f=lane&15, row=w=(lane>>4)*4+reg ; fused bias; float4 stores
        const int fb = f0h * 32 + l15;
        #pragma unroll
        for (int s = 0; s < 4; ++s) {
            int wg = w0 + whb + s * 16 + lg * 4;
            if (wg < OW_) {                // wg%4==0 and OW_%4==0 -> whole float4 in-range
                float4 o0, o1;
                o0.x = acc[s][0][0] + bv0; o0.y = acc[s][0][1] + bv0;
                o0.z = acc[s][0][2] + bv0; o0.w = acc[s][0][3] + bv0;
                o1.x = acc[s][1][0] + bv1; o1.y = acc[s][1][1] + bv1;
                o1.z = acc[s][1][2] + bv1; o1.w = acc[s][1][3] + bv1;
                *reinterpret_cast<float4*>(out + ((size_t)(n * F_ + fb) * OW_ + wg))      = o0;
                *reinterpret_cast<float4*>(out + ((size_t)(n * F_ + fb + 16) * OW_ + wg)) = o1;
            }
        }
    };

    // ---- pipelined 2-tile flow ----
    LOADS(wbase);                 // tile 0 global loads
    WRITE(0);                     // convert + swizzled LDS write (waits loads)
    LOADS(wbase + WBLK);          // tile 1 loads issued EARLY (hide under compute)
    __syncthreads();
    COMPUTE(0, wbase);            // MFMA + stores for tile 0
    WRITE(1);                     // tile-1 loads arrived during compute; write buf1
    __syncthreads();
    COMPUTE(1, wbase + WBLK);     // tile 1
}

extern "C" void kernel_launch(void* const* d_in, const int* in_sizes, int n_in,
                              void* d_out, int out_size, void* d_ws, size_t ws_size,
                              hipStream_t stream) {
    const float* x    = (const float*)d_in[0];
    const float* filt = (const float*)d_in[1];
    const float* bias = (const float*)d_in[2];
    float* out        = (float*)d_out;

    unsigned short* filtB = (unsigned short*)d_ws;   // 9*64*64 bf16 = 73728 B

    prep_filt_k<<<(WW_ * F_ * C_ + 255) / 256, 256, 0, stream>>>(filt, filtB);

    dim3 grid(STRIPES, N_);
    conv_k<<<grid, 256, 0, stream>>>(x, filtB, bias, out);
}

// Round 4
// 44.054 us; speedup vs baseline: 1.8934x; 1.2485x over previous
//
#include <hip/hip_runtime.h>
#include <stdint.h>

#define N_   64
#define C_   64
#define W_   4096
#define F_   64
#define WW_  9
#define OW_  4088        // W_ - WW_ + 1
#define WBLK 128
#define WROWS 136        // WBLK + 8 halo

typedef __bf16 bf16x8 __attribute__((ext_vector_type(8)));
typedef float  f32x4  __attribute__((ext_vector_type(4)));

__device__ __forceinline__ unsigned short f2bf(float f) {
    union { float f; uint32_t u; } v; v.f = f;
    uint32_t u = v.u;
    return (unsigned short)((u + 0x7FFFu + ((u >> 16) & 1u)) >> 16);  // RNE
}

// filt fp32 [F][C][WW] -> filtB bf16, fragment-major [t][f0h][m][u][lane][8j]
//   f = f0h*32 + u*16 + (lane&15),  c = m*32 + (lane>>4)*8 + j
// Each B-fragment load in the main kernel is ONE contiguous 1KB wave load.
__global__ __launch_bounds__(256) void prep_filt_k(const float* __restrict__ filt,
                                                   unsigned short* __restrict__ filtB) {
    int id = blockIdx.x * 256 + threadIdx.x;
    if (id < WW_ * F_ * C_) {
        int j    = id & 7;
        int lane = (id >> 3) & 63;
        int u    = (id >> 9) & 1;
        int m    = (id >> 10) & 1;
        int f0h  = (id >> 11) & 1;
        int t    = id >> 12;
        int l15  = lane & 15, lg = lane >> 4;
        int f = f0h * 32 + u * 16 + l15;
        int c = m * 32 + lg * 8 + j;
        filtB[id] = f2bf(filt[(f * C_ + c) * WW_ + t]);
    }
}

// One block = one (n, 128-w tile), all 64 filters. 4 waves.
// Staging: register-transpose 4c x 4w micro-tiles -> ds_write_b64, swizzled.
// No registers held across the barrier -> no spill; 4 blocks/CU for TLP.
__global__ __launch_bounds__(256, 4) void conv_k(const float* __restrict__ x,
                                                 const unsigned short* __restrict__ filtB,
                                                 const float* __restrict__ bias,
                                                 float* __restrict__ out) {
    __shared__ unsigned short xs[WROWS * 64];   // 17408 B, swizzled rows of 128B

    const int tid  = threadIdx.x;
    const int lane = tid & 63;
    const int wv   = tid >> 6;
    const int n    = blockIdx.y;
    const int w0   = blockIdx.x * WBLK;

    // ---- staging: x[c][w0..w0+135] f32 -> xs[w][c] bf16, chunk-XOR swizzled ----
    // Main 128 w: thread owns c4 = wv*16 + ((tid>>4)&3)*4, w = (tid&15)*4 (+j*64).
    // Per load instr: 4 c-rows x 256B contiguous (good coalescing).
    {
        const int c4 = (wv << 4) + (((tid >> 4) & 3) << 2);
        const int wq = (tid & 15) << 2;
        const int cg = c4 >> 3;
        const int cs = c4 & 7;             // 0 or 4
        const float* xb = x + ((size_t)(n * C_ + c4)) * W_ + w0;
        #pragma unroll
        for (int j = 0; j < 2; ++j) {
            const int wl = wq + j * 64;    // w0+wl+3 <= 4095 always: in-bounds
            float4 r0 = *reinterpret_cast<const float4*>(xb + 0 * W_ + wl);
            float4 r1 = *reinterpret_cast<const float4*>(xb + 1 * W_ + wl);
            float4 r2 = *reinterpret_cast<const float4*>(xb + 2 * W_ + wl);
            float4 r3 = *reinterpret_cast<const float4*>(xb + 3 * W_ + wl);
            const float* p0 = &r0.x; const float* p1 = &r1.x;
            const float* p2 = &r2.x; const float* p3 = &r3.x;
            #pragma unroll
            for (int jj = 0; jj < 4; ++jj) {
                int w = wl + jj;
                ushort4 u;
                u.x = f2bf(p0[jj]); u.y = f2bf(p1[jj]);
                u.z = f2bf(p2[jj]); u.w = f2bf(p3[jj]);
                *reinterpret_cast<ushort4*>(&xs[w * 64 + ((cg ^ (w & 7)) << 3) + cs]) = u;
            }
        }
        // Halo w = 128..135 (8 w x 64 c), threads 0..31, guarded scalar loads.
        if (tid < 32) {
            const int hc4 = (tid & 15) << 2;
            const int hwl = 128 + ((tid >> 4) << 2);
            const int hcg = hc4 >> 3;
            const int hcs = hc4 & 7;
            #pragma unroll
            for (int jj = 0; jj < 4; ++jj) {
                int w  = hwl + jj;
                int gw = w0 + w;
                ushort4 u;
                if (gw < W_) {
                    const float* hp = x + ((size_t)(n * C_ + hc4)) * W_ + gw;
                    u.x = f2bf(hp[0]);
                    u.y = f2bf(hp[(size_t)W_]);
                    u.z = f2bf(hp[(size_t)2 * W_]);
                    u.w = f2bf(hp[(size_t)3 * W_]);
                } else {
                    u.x = u.y = u.z = u.w = 0;
                }
                *reinterpret_cast<ushort4*>(&xs[w * 64 + ((hcg ^ (w & 7)) << 3) + hcs]) = u;
            }
        }
    }
    __syncthreads();

    // ---- compute: wave quadrant = 64w x 32f ----
    const int f0h = wv & 1;
    const int whb = (wv >> 1) * 64;
    const int l15 = lane & 15;
    const int lg  = lane >> 4;

    const unsigned short* Bb = filtB + f0h * 2048 + lane * 8;
    const float bv0 = 64.0f * bias[f0h * 32 + l15];        // reference adds bias per channel -> C*bias
    const float bv1 = 64.0f * bias[f0h * 32 + 16 + l15];

    f32x4 acc[4][2];
    #pragma unroll
    for (int s = 0; s < 4; ++s) {
        acc[s][0] = (f32x4){0.f, 0.f, 0.f, 0.f};
        acc[s][1] = (f32x4){0.f, 0.f, 0.f, 0.f};
    }

    bf16x8 Bc[4], Bn[4];
    #pragma unroll
    for (int q = 0; q < 4; ++q)            // frag (m=q>>1, u=q&1), t=0
        Bc[q] = *reinterpret_cast<const bf16x8*>(Bb + (q >> 1) * 1024 + (q & 1) * 512);

    #pragma unroll
    for (int t = 0; t < WW_; ++t) {
        if (t < WW_ - 1) {
            #pragma unroll
            for (int q = 0; q < 4; ++q)
                Bn[q] = *reinterpret_cast<const bf16x8*>(Bb + (t + 1) * 4096 + (q >> 1) * 1024 + (q & 1) * 512);
        }
        #pragma unroll
        for (int m = 0; m < 2; ++m) {
            #pragma unroll
            for (int s = 0; s < 4; ++s) {
                int row   = whb + s * 16 + l15 + t;              // <= 135
                int chunk = ((m << 2) | lg) ^ (row & 7);
                bf16x8 a  = *reinterpret_cast<const bf16x8*>(&xs[row * 64 + chunk * 8]);
                acc[s][0] = __builtin_amdgcn_mfma_f32_16x16x32_bf16(a, Bc[m * 2 + 0], acc[s][0], 0, 0, 0);
                acc[s][1] = __builtin_amdgcn_mfma_f32_16x16x32_bf16(a, Bc[m * 2 + 1], acc[s][1], 0, 0, 0);
            }
        }
        if (t < WW_ - 1) {
            #pragma unroll
            for (int q = 0; q < 4; ++q) Bc[q] = Bn[q];
        }
    }

    // ---- epilogue: D col=f=lane&15, row=w=(lane>>4)*4+reg ; fused bias; float4 stores ----
    const int fb = f0h * 32 + l15;
    #pragma unroll
    for (int s = 0; s < 4; ++s) {
        int wg = w0 + whb + s * 16 + lg * 4;
        if (wg < OW_) {                    // wg%4==0, OW_%4==0 -> whole float4 in-range
            float4 o0, o1;
            o0.x = acc[s][0][0] + bv0; o0.y = acc[s][0][1] + bv0;
            o0.z = acc[s][0][2] + bv0; o0.w = acc[s][0][3] + bv0;
            o1.x = acc[s][1][0] + bv1; o1.y = acc[s][1][1] + bv1;
            o1.z = acc[s][1][2] + bv1; o1.w = acc[s][1][3] + bv1;
            *reinterpret_cast<float4*>(out + ((size_t)(n * F_ + fb) * OW_ + wg))      = o0;
            *reinterpret_cast<float4*>(out + ((size_t)(n * F_ + fb + 16) * OW_ + wg)) = o1;
        }
    }
}

extern "C" void kernel_launch(void* const* d_in, const int* in_sizes, int n_in,
                              void* d_out, int out_size, void* d_ws, size_t ws_size,
                              hipStream_t stream) {
    const float* x    = (const float*)d_in[0];
    const float* filt = (const float*)d_in[1];
    const float* bias = (const float*)d_in[2];
    float* out        = (float*)d_out;

    unsigned short* filtB = (unsigned short*)d_ws;   // 9*64*64 bf16 = 73728 B

    prep_filt_k<<<(WW_ * F_ * C_ + 255) / 256, 256, 0, stream>>>(filt, filtB);

    dim3 grid(W_ / WBLK, N_);   // 32 x 64 = 2048 blocks
    conv_k<<<grid, 256, 0, stream>>>(x, filtB, bias, out);
}